// Round 2
// baseline (5855.164 us; speedup 1.0000x reference)
//
#include <hip/hip_runtime.h>
#include <hip/hip_bf16.h>
#include <cmath>

// Problem: N=64, T=512, D=512, H=512
//   xw = x @ Wx + b            (parallel GEMM, kernel A -> d_out)
//   h_t = tanh(xw_t + h_{t-1} @ Wh)   (sequential, kernel B)
//
// R2 design: recurrence uses 4 workgroups per sequence (j-split of Wh into
// 128-column slices), 256 wgs x 1024 threads = 1 wg/CU on all 256 CUs.
// Each wg holds its 256 KB Wh slice entirely in VGPRs (64 regs/thread),
// eliminating the per-step 1 MB L2 stream that bound R1 (135 GB/s per CU).
// The 4 wgs of a sequence exchange h-parts per step via a double-buffered
// global buffer + per-part release counters (agent-scope atomics).

#define DH    512
#define NSEQ  64
#define TSTEPS 512
#define MTOT  32768   // N*T

// ---------------- Kernel A: xw = x @ Wx + b  (fp32 LDS-tiled GEMM) ----------
__global__ __launch_bounds__(256) void xw_gemm(
    const float* __restrict__ X,    // (32768, 512)
    const float* __restrict__ Wx,   // (512, 512)
    const float* __restrict__ b,    // (512,)
    float* __restrict__ XW)         // (32768, 512) == d_out
{
    __shared__ float As[16][64];   // [k][m]
    __shared__ float Bs[16][64];   // [k][j]

    const int bm = blockIdx.x * 64;
    const int bn = blockIdx.y * 64;
    const int tid = threadIdx.x;
    const int tr = tid >> 4;
    const int tc = tid & 15;

    float acc[4][4] = {};

    for (int k0 = 0; k0 < DH; k0 += 16) {
        {
            int m  = tid >> 2;
            int kk = (tid & 3) * 4;
            const float4 v = *(const float4*)&X[(size_t)(bm + m) * DH + k0 + kk];
            As[kk + 0][m] = v.x; As[kk + 1][m] = v.y;
            As[kk + 2][m] = v.z; As[kk + 3][m] = v.w;
        }
        {
            int k  = tid >> 4;
            int j4 = (tid & 15) * 4;
            *(float4*)&Bs[k][j4] = *(const float4*)&Wx[(size_t)(k0 + k) * DH + bn + j4];
        }
        __syncthreads();

        #pragma unroll
        for (int k = 0; k < 16; ++k) {
            float a0 = As[k][tr * 4 + 0], a1 = As[k][tr * 4 + 1];
            float a2 = As[k][tr * 4 + 2], a3 = As[k][tr * 4 + 3];
            float b0 = Bs[k][tc * 4 + 0], b1 = Bs[k][tc * 4 + 1];
            float b2 = Bs[k][tc * 4 + 2], b3 = Bs[k][tc * 4 + 3];
            acc[0][0] += a0 * b0; acc[0][1] += a0 * b1; acc[0][2] += a0 * b2; acc[0][3] += a0 * b3;
            acc[1][0] += a1 * b0; acc[1][1] += a1 * b1; acc[1][2] += a1 * b2; acc[1][3] += a1 * b3;
            acc[2][0] += a2 * b0; acc[2][1] += a2 * b1; acc[2][2] += a2 * b2; acc[2][3] += a2 * b3;
            acc[3][0] += a3 * b0; acc[3][1] += a3 * b1; acc[3][2] += a3 * b2; acc[3][3] += a3 * b3;
        }
        __syncthreads();
    }

    #pragma unroll
    for (int i = 0; i < 4; ++i) {
        const size_t row = (size_t)(bm + tr * 4 + i);
        #pragma unroll
        for (int j = 0; j < 4; ++j) {
            const int col = bn + tc * 4 + j;
            XW[row * DH + col] = acc[i][j] + b[col];
        }
    }
}

// ---------------- Kernel B (R2): 4 wgs per sequence, Wh in VGPRs ------------
// wg -> (seq, part): sequences grouped so a sequence's 4 parts land on the
// same XCD under round-robin dispatch (perf heuristic only; correctness via
// agent-scope atomics regardless of placement).
// Thread layout: jgrp = tid&31 -> cols [part*128 + jgrp*4, +4)
//                ks   = tid>>5 -> k-slice [ks*16, ks*16+16)
// Weights: w4[16] = Wh[ks*16+kk][part*128 + jgrp*4 .. +4)  (64 VGPRs)
__global__ __launch_bounds__(1024, 4) void rnn_rec4(
    const float* __restrict__ Wh,   // (512, 512)
    const float* __restrict__ h0,   // (64, 512)
    float* __restrict__ out,        // (64, 512, 512); holds xw on entry
    float* __restrict__ hbuf,       // (2, 64, 512) exchange buffer (d_ws)
    unsigned int* __restrict__ cnt) // (64, 4) step counters (d_ws), zeroed
{
    __shared__ float hsh[DH];
    __shared__ float partb[32][132];   // padded; 132*4 B row = 16B-aligned

    const int bid  = blockIdx.x;
    const int xcd  = bid & 7;
    const int idx  = bid >> 3;          // 0..31
    const int seq  = xcd * 8 + (idx & 7);
    const int part = idx >> 3;          // 0..3
    const int tid  = threadIdx.x;
    const int jgrp = tid & 31;
    const int ks   = tid >> 5;          // 0..31
    const int colbase = part * 128;

    // ---- one-time: weights into registers (coalesced float4 per wave) ----
    float4 w4[16];
    #pragma unroll
    for (int kk = 0; kk < 16; ++kk)
        w4[kk] = *(const float4*)&Wh[(size_t)(ks * 16 + kk) * DH + colbase + jgrp * 4];

    if (tid < DH) hsh[tid] = h0[(size_t)seq * DH + tid];
    __syncthreads();

    float* __restrict__ outn = out + (size_t)seq * TSTEPS * DH;
    const int mycol = colbase + tid;            // valid for tid < 128
    float xw_cur = (tid < 128) ? outn[mycol] : 0.0f;

    unsigned* __restrict__ mycnt = &cnt[seq * 4];

    for (int t = 0; t < TSTEPS; ++t) {
        // prefetch next step's xw (consumed ~1 us later)
        float xw_next = 0.0f;
        if (tid < 128 && t < TSTEPS - 1)
            xw_next = outn[(size_t)(t + 1) * DH + mycol];

        // ---- partial GEMM: acc[j] = sum_{k in slice} h[k] * Wh[k][j] ----
        float4 hv[4];
        #pragma unroll
        for (int q = 0; q < 4; ++q)
            hv[q] = *(const float4*)&hsh[ks * 16 + q * 4];
        const float* hvp = (const float*)hv;

        float4 acc = {0.0f, 0.0f, 0.0f, 0.0f};
        #pragma unroll
        for (int kk = 0; kk < 16; ++kk) {
            const float hk = hvp[kk];
            acc.x += hk * w4[kk].x;
            acc.y += hk * w4[kk].y;
            acc.z += hk * w4[kk].z;
            acc.w += hk * w4[kk].w;
        }
        *(float4*)&partb[ks][jgrp * 4] = acc;
        __syncthreads();

        // ---- level-2 reduce + tanh + publish (threads 0..127) ----
        float* hb = &hbuf[((size_t)(t & 1) * NSEQ + seq) * DH];
        if (tid < 128) {
            float s = 0.0f;
            #pragma unroll
            for (int r = 0; r < 32; ++r) s += partb[r][tid];
            const float hval = tanhf(xw_cur + s);
            outn[(size_t)t * DH + mycol] = hval;
            hsh[mycol] = hval;
            __hip_atomic_store((unsigned*)&hb[mycol], __float_as_uint(hval),
                               __ATOMIC_RELAXED, __HIP_MEMORY_SCOPE_AGENT);
            xw_cur = xw_next;
        }
        __syncthreads();   // drains vmcnt: part stores are at the coherence point

        if (tid == 0) {
            __threadfence();
            __hip_atomic_store(&mycnt[part], (unsigned)(t + 1),
                               __ATOMIC_RELEASE, __HIP_MEMORY_SCOPE_AGENT);
        }
        // poll the 3 partner counters (3 lanes in parallel)
        if (tid < 4 && tid != part) {
            while (__hip_atomic_load(&mycnt[tid], __ATOMIC_ACQUIRE,
                                     __HIP_MEMORY_SCOPE_AGENT) < (unsigned)(t + 1)) {}
        }
        __syncthreads();

        // ---- pull the 384 remote h values into LDS ----
        if (tid < DH && (tid >> 7) != part) {
            hsh[tid] = __uint_as_float(
                __hip_atomic_load((const unsigned*)&hb[tid],
                                  __ATOMIC_RELAXED, __HIP_MEMORY_SCOPE_AGENT));
        }
        __syncthreads();
    }
}

// ---------------- Fallback (R1 kernel) if ws_size is too small --------------
__global__ __launch_bounds__(1024) void rnn_rec(
    const float* __restrict__ Wh,
    const float* __restrict__ h0,
    float* __restrict__ out)
{
    __shared__ float hsh[DH];
    __shared__ float part[8][DH];

    const int n     = blockIdx.x;
    const int tid   = threadIdx.x;
    const int jgrp  = tid & 127;
    const int ks    = tid >> 7;
    const int kbase = ks * 64;

    if (tid < DH) hsh[tid] = h0[(size_t)n * DH + tid];
    __syncthreads();

    const float4* __restrict__ Wh4 = (const float4*)Wh;
    float* __restrict__ outn = out + (size_t)n * TSTEPS * DH;

    float xw_cur = (tid < DH) ? outn[tid] : 0.0f;

    for (int t = 0; t < TSTEPS; ++t) {
        float xw_next = 0.0f;
        if (tid < DH && t < TSTEPS - 1) xw_next = outn[(size_t)(t + 1) * DH + tid];

        float4 acc = {0.0f, 0.0f, 0.0f, 0.0f};
        #pragma unroll 8
        for (int k = 0; k < 64; ++k) {
            const float hk = hsh[kbase + k];
            const float4 w = Wh4[(size_t)(kbase + k) * 128 + jgrp];
            acc.x += hk * w.x; acc.y += hk * w.y;
            acc.z += hk * w.z; acc.w += hk * w.w;
        }
        *(float4*)&part[ks][jgrp * 4] = acc;
        __syncthreads();

        if (tid < DH) {
            const int j = tid;
            float s = part[0][j] + part[1][j] + part[2][j] + part[3][j]
                    + part[4][j] + part[5][j] + part[6][j] + part[7][j];
            const float hv = tanhf(xw_cur + s);
            hsh[j] = hv;
            outn[(size_t)t * DH + j] = hv;
            xw_cur = xw_next;
        }
        __syncthreads();
    }
}

extern "C" void kernel_launch(void* const* d_in, const int* in_sizes, int n_in,
                              void* d_out, int out_size, void* d_ws, size_t ws_size,
                              hipStream_t stream) {
    const float* x  = (const float*)d_in[0];  // (64, 512, 512)
    const float* h0 = (const float*)d_in[1];  // (64, 512)
    const float* Wx = (const float*)d_in[2];  // (512, 512)
    const float* Wh = (const float*)d_in[3];  // (512, 512)
    const float* b  = (const float*)d_in[4];  // (512,)
    float* out = (float*)d_out;               // (64, 512, 512)

    // Kernel A: xw = x @ Wx + b, written into d_out.
    xw_gemm<<<dim3(MTOT / 64, DH / 64), 256, 0, stream>>>(x, Wx, b, out);

    // Workspace layout: [cnt: 64*4 u32 = 1 KB][hbuf: 2*64*512 f32 = 256 KB]
    const size_t cnt_bytes  = (size_t)NSEQ * 4 * sizeof(unsigned);
    const size_t hbuf_bytes = (size_t)2 * NSEQ * DH * sizeof(float);
    if (ws_size >= cnt_bytes + hbuf_bytes + 1024) {
        unsigned* cnt = (unsigned*)d_ws;
        float* hbuf   = (float*)((char*)d_ws + 1024);
        // zero the counters every launch (graph-replay deterministic)
        hipMemsetAsync(cnt, 0, cnt_bytes, stream);
        rnn_rec4<<<256, 1024, 0, stream>>>(Wh, h0, out, hbuf, cnt);
    } else {
        rnn_rec<<<NSEQ, 1024, 0, stream>>>(Wh, h0, out);
    }
}

// Round 3
// 1868.520 us; speedup vs baseline: 3.1336x; 3.1336x over previous
//
#include <hip/hip_runtime.h>
#include <hip/hip_bf16.h>
#include <cmath>

// Problem: N=64, T=512, D=512, H=512
//   xw = x @ Wx + b                 (parallel GEMM, kernel A -> d_out)
//   h_t = tanh(xw_t + h_{t-1} @ Wh) (sequential, kernel B)
//
// R3: 4 wgs per sequence (128-column j-slices of Wh), 256 wgs x 512 threads
// = 1 wg/CU on all 256 CUs. Each wg holds its 256 KB Wh slice in VGPRs
// (float2 wv[64] = 128 regs/thread, static indexing, no launch_bounds reg cap).
// Cross-wg h exchange per step uses RELAXED agent-scope atomics ONLY (no
// threadfence, no release/acquire -> no per-step L2 writeback, which is what
// killed R2: WRITE_SIZE 64->132 MB). Ordering: producer waits vmcnt(0) +
// barrier before flag store; consumer polls flag then loads (same coherence
// point => visibility guaranteed).

#define DH     512
#define NSEQ   64
#define TSTEPS 512
#define MTOT   32768   // N*T

// ---------------- Kernel A: xw = x @ Wx + b  (fp32 LDS-tiled GEMM) ----------
__global__ __launch_bounds__(256) void xw_gemm(
    const float* __restrict__ X,    // (32768, 512)
    const float* __restrict__ Wx,   // (512, 512)
    const float* __restrict__ b,    // (512,)
    float* __restrict__ XW)         // (32768, 512) == d_out
{
    __shared__ float As[16][64];
    __shared__ float Bs[16][64];

    const int bm = blockIdx.x * 64;
    const int bn = blockIdx.y * 64;
    const int tid = threadIdx.x;
    const int tr = tid >> 4;
    const int tc = tid & 15;

    float acc[4][4] = {};

    for (int k0 = 0; k0 < DH; k0 += 16) {
        {
            int m  = tid >> 2;
            int kk = (tid & 3) * 4;
            const float4 v = *(const float4*)&X[(size_t)(bm + m) * DH + k0 + kk];
            As[kk + 0][m] = v.x; As[kk + 1][m] = v.y;
            As[kk + 2][m] = v.z; As[kk + 3][m] = v.w;
        }
        {
            int k  = tid >> 4;
            int j4 = (tid & 15) * 4;
            *(float4*)&Bs[k][j4] = *(const float4*)&Wx[(size_t)(k0 + k) * DH + bn + j4];
        }
        __syncthreads();

        #pragma unroll
        for (int k = 0; k < 16; ++k) {
            float a0 = As[k][tr * 4 + 0], a1 = As[k][tr * 4 + 1];
            float a2 = As[k][tr * 4 + 2], a3 = As[k][tr * 4 + 3];
            float b0 = Bs[k][tc * 4 + 0], b1 = Bs[k][tc * 4 + 1];
            float b2 = Bs[k][tc * 4 + 2], b3 = Bs[k][tc * 4 + 3];
            acc[0][0] += a0 * b0; acc[0][1] += a0 * b1; acc[0][2] += a0 * b2; acc[0][3] += a0 * b3;
            acc[1][0] += a1 * b0; acc[1][1] += a1 * b1; acc[1][2] += a1 * b2; acc[1][3] += a1 * b3;
            acc[2][0] += a2 * b0; acc[2][1] += a2 * b1; acc[2][2] += a2 * b2; acc[2][3] += a2 * b3;
            acc[3][0] += a3 * b0; acc[3][1] += a3 * b1; acc[3][2] += a3 * b2; acc[3][3] += a3 * b3;
        }
        __syncthreads();
    }

    #pragma unroll
    for (int i = 0; i < 4; ++i) {
        const size_t row = (size_t)(bm + tr * 4 + i);
        #pragma unroll
        for (int j = 0; j < 4; ++j) {
            const int col = bn + tc * 4 + j;
            XW[row * DH + col] = acc[i][j] + b[col];
        }
    }
}

// ---------------- Kernel B (R3): 4 wgs/seq, Wh in VGPRs, relaxed-atomic sync
// Thread layout (512 threads): cp = tid&63 -> column pair, s = tid>>6 -> k-slice
//   cols  c0 = part*128 + cp*2, c0+1
//   k in [s*64, s*64+64)
// Weights: float2 wv[64] = Wh[s*64+k][c0..c0+1]  (128 VGPRs, static)
__global__ __launch_bounds__(512) void rnn_rec4b(
    const float* __restrict__ Wh,   // (512, 512)
    const float* __restrict__ h0,   // (64, 512)
    float* __restrict__ out,        // (64, 512, 512); holds xw on entry
    float* __restrict__ hbuf,       // (2, 64, 512) exchange buffer (d_ws)
    unsigned int* __restrict__ cnt) // (64, 4) step flags (d_ws), zeroed/launch
{
    __shared__ float hsh[DH];
    __shared__ float partb[8][DH / 4];   // 8 k-slices x 128 cols

    const int bid  = blockIdx.x;
    // parts of a sequence land on the same XCD under round-robin (heuristic;
    // correctness is placement-independent via agent-scope atomics)
    const int xcd  = bid & 7;
    const int idx  = bid >> 3;           // 0..31
    const int seq  = xcd * 8 + (idx & 7);
    const int part = idx >> 3;           // 0..3
    const int tid  = threadIdx.x;
    const int cp   = tid & 63;
    const int s    = tid >> 6;           // 0..7
    const int colbase = part * 128;
    const int c0   = colbase + cp * 2;

    // ---- one-time: weight slice into registers (coalesced float2) ----
    float2 wv[64];
    #pragma unroll
    for (int k = 0; k < 64; ++k)
        wv[k] = *(const float2*)&Wh[(size_t)(s * 64 + k) * DH + c0];

    if (tid < DH) hsh[tid] = h0[(size_t)seq * DH + tid];
    __syncthreads();

    float* __restrict__ outn = out + (size_t)seq * TSTEPS * DH;
    const int mycol = colbase + tid;     // valid for tid < 128
    float xw_cur = (tid < 128) ? outn[mycol] : 0.0f;

    unsigned* __restrict__ mycnt = &cnt[seq * 4];

    for (int t = 0; t < TSTEPS; ++t) {
        // prefetch next xw early (latency hides under this step)
        float xw_next = 0.0f;
        if (tid < 128 && t < TSTEPS - 1)
            xw_next = outn[(size_t)(t + 1) * DH + mycol];

        // ---- partial dot: 64 k's x 2 cols, h via LDS broadcast reads ----
        float a0 = 0.0f, a1 = 0.0f;
        #pragma unroll
        for (int q = 0; q < 16; ++q) {
            const float4 h4 = *(const float4*)&hsh[s * 64 + q * 4];
            a0 += h4.x * wv[4 * q + 0].x; a1 += h4.x * wv[4 * q + 0].y;
            a0 += h4.y * wv[4 * q + 1].x; a1 += h4.y * wv[4 * q + 1].y;
            a0 += h4.z * wv[4 * q + 2].x; a1 += h4.z * wv[4 * q + 2].y;
            a0 += h4.w * wv[4 * q + 3].x; a1 += h4.w * wv[4 * q + 3].y;
        }
        partb[s][cp * 2 + 0] = a0;
        partb[s][cp * 2 + 1] = a1;
        __syncthreads();

        float* hb = &hbuf[((size_t)(t & 1) * NSEQ + seq) * DH];

        // ---- reduce + tanh + publish (threads 0..127) ----
        if (tid < 128) {
            float ssum = partb[0][tid] + partb[1][tid] + partb[2][tid] + partb[3][tid]
                       + partb[4][tid] + partb[5][tid] + partb[6][tid] + partb[7][tid];
            const float hval = tanhf(xw_cur + ssum);
            outn[(size_t)t * DH + mycol] = hval;
            hsh[mycol] = hval;
            if (t < TSTEPS - 1)
                __hip_atomic_store(&hb[mycol], hval,
                                   __ATOMIC_RELAXED, __HIP_MEMORY_SCOPE_AGENT);
            xw_cur = xw_next;
            // drain this wave's stores to the coherence point (no cache flush)
            asm volatile("s_waitcnt vmcnt(0)" ::: "memory");
        }
        __syncthreads();   // waves 0,1 have drained => data globally visible

        if (t < TSTEPS - 1) {
            if (tid == 0)
                __hip_atomic_store(&mycnt[part], (unsigned)(t + 1),
                                   __ATOMIC_RELAXED, __HIP_MEMORY_SCOPE_AGENT);
            // 3 lanes poll the 3 partner flags
            if (tid < 4 && tid != part) {
                while (__hip_atomic_load(&mycnt[tid], __ATOMIC_RELAXED,
                                         __HIP_MEMORY_SCOPE_AGENT) < (unsigned)(t + 1)) {}
            }
            __syncthreads();
            asm volatile("" ::: "memory");   // no hoisting loads above poll

            // ---- pull 384 remote h values into LDS ----
            if (tid < DH && (tid >> 7) != part) {
                hsh[tid] = __hip_atomic_load(&hb[tid], __ATOMIC_RELAXED,
                                             __HIP_MEMORY_SCOPE_AGENT);
            }
        }
        __syncthreads();
    }
}

// ---------------- Fallback (R1 kernel) if ws_size is too small --------------
__global__ __launch_bounds__(1024) void rnn_rec(
    const float* __restrict__ Wh,
    const float* __restrict__ h0,
    float* __restrict__ out)
{
    __shared__ float hsh[DH];
    __shared__ float part[8][DH];

    const int n     = blockIdx.x;
    const int tid   = threadIdx.x;
    const int jgrp  = tid & 127;
    const int ks    = tid >> 7;
    const int kbase = ks * 64;

    if (tid < DH) hsh[tid] = h0[(size_t)n * DH + tid];
    __syncthreads();

    const float4* __restrict__ Wh4 = (const float4*)Wh;
    float* __restrict__ outn = out + (size_t)n * TSTEPS * DH;

    float xw_cur = (tid < DH) ? outn[tid] : 0.0f;

    for (int t = 0; t < TSTEPS; ++t) {
        float xw_next = 0.0f;
        if (tid < DH && t < TSTEPS - 1) xw_next = outn[(size_t)(t + 1) * DH + tid];

        float4 acc = {0.0f, 0.0f, 0.0f, 0.0f};
        #pragma unroll 8
        for (int k = 0; k < 64; ++k) {
            const float hk = hsh[kbase + k];
            const float4 w = Wh4[(size_t)(kbase + k) * 128 + jgrp];
            acc.x += hk * w.x; acc.y += hk * w.y;
            acc.z += hk * w.z; acc.w += hk * w.w;
        }
        *(float4*)&part[ks][jgrp * 4] = acc;
        __syncthreads();

        if (tid < DH) {
            const int j = tid;
            float sum = part[0][j] + part[1][j] + part[2][j] + part[3][j]
                      + part[4][j] + part[5][j] + part[6][j] + part[7][j];
            const float hv = tanhf(xw_cur + sum);
            hsh[j] = hv;
            outn[(size_t)t * DH + j] = hv;
            xw_cur = xw_next;
        }
        __syncthreads();
    }
}

extern "C" void kernel_launch(void* const* d_in, const int* in_sizes, int n_in,
                              void* d_out, int out_size, void* d_ws, size_t ws_size,
                              hipStream_t stream) {
    const float* x  = (const float*)d_in[0];  // (64, 512, 512)
    const float* h0 = (const float*)d_in[1];  // (64, 512)
    const float* Wx = (const float*)d_in[2];  // (512, 512)
    const float* Wh = (const float*)d_in[3];  // (512, 512)
    const float* b  = (const float*)d_in[4];  // (512,)
    float* out = (float*)d_out;               // (64, 512, 512)

    // Kernel A: xw = x @ Wx + b, written into d_out.
    xw_gemm<<<dim3(MTOT / 64, DH / 64), 256, 0, stream>>>(x, Wx, b, out);

    // Workspace layout: [cnt: 64*4 u32 (1 KB slot)][hbuf: 2*64*512 f32]
    const size_t cnt_bytes  = (size_t)NSEQ * 4 * sizeof(unsigned);
    const size_t hbuf_bytes = (size_t)2 * NSEQ * DH * sizeof(float);
    if (ws_size >= cnt_bytes + hbuf_bytes + 1024) {
        unsigned* cnt = (unsigned*)d_ws;
        float* hbuf   = (float*)((char*)d_ws + 1024);
        hipMemsetAsync(cnt, 0, cnt_bytes, stream);  // deterministic per replay
        rnn_rec4b<<<256, 512, 0, stream>>>(Wh, h0, out, hbuf, cnt);
    } else {
        rnn_rec<<<NSEQ, 1024, 0, stream>>>(Wh, h0, out);
    }
}

// Round 4
// 927.829 us; speedup vs baseline: 6.3106x; 2.0139x over previous
//
#include <hip/hip_runtime.h>
#include <hip/hip_bf16.h>
#include <cmath>

// Problem: N=64, T=512, D=512, H=512
//   xw = x @ Wx + b                 (parallel GEMM, kernel A -> d_out)
//   h_t = tanh(xw_t + h_{t-1} @ Wh) (sequential, kernel B)
//
// R4: 4 wgs per sequence (128-col j-slices of Wh), 256 wgs x 512 thr = 1 wg/CU.
// Fixes over R3 (which ran at 3.2 us/step):
//  (a) Weights truly register-resident: __launch_bounds__(512,2) allows 256
//      VGPRs/wave; asm "+v" pin after the one-time load prevents the compiler
//      from rematerializing the loads inside the t-loop (R3: VGPR_Count=84
//      proved the 128-reg weight array was being re-streamed from L2 every
//      step, ~1.9 us/step).
//  (b) Sync = self-tagged 8-byte atomic publishes {tag=t+1, h} (relaxed,
//      agent scope). No flags, no threadfence, no vmcnt drain: a consumer
//      polls its slot and the tag+data arrive in the same atomic word.
//      Waves 0-1 do reduce+tanh+publish; waves 2-7 poll remote slots
//      concurrently. One barrier per step.

#define DH     512
#define NSEQ   64
#define TSTEPS 512
#define MTOT   32768   // N*T

// ---------------- Kernel A: xw = x @ Wx + b  (fp32 LDS-tiled GEMM) ----------
__global__ __launch_bounds__(256) void xw_gemm(
    const float* __restrict__ X,    // (32768, 512)
    const float* __restrict__ Wx,   // (512, 512)
    const float* __restrict__ b,    // (512,)
    float* __restrict__ XW)         // (32768, 512) == d_out
{
    __shared__ float As[16][64];
    __shared__ float Bs[16][64];

    const int bm = blockIdx.x * 64;
    const int bn = blockIdx.y * 64;
    const int tid = threadIdx.x;
    const int tr = tid >> 4;
    const int tc = tid & 15;

    float acc[4][4] = {};

    for (int k0 = 0; k0 < DH; k0 += 16) {
        {
            int m  = tid >> 2;
            int kk = (tid & 3) * 4;
            const float4 v = *(const float4*)&X[(size_t)(bm + m) * DH + k0 + kk];
            As[kk + 0][m] = v.x; As[kk + 1][m] = v.y;
            As[kk + 2][m] = v.z; As[kk + 3][m] = v.w;
        }
        {
            int k  = tid >> 4;
            int j4 = (tid & 15) * 4;
            *(float4*)&Bs[k][j4] = *(const float4*)&Wx[(size_t)(k0 + k) * DH + bn + j4];
        }
        __syncthreads();

        #pragma unroll
        for (int k = 0; k < 16; ++k) {
            float a0 = As[k][tr * 4 + 0], a1 = As[k][tr * 4 + 1];
            float a2 = As[k][tr * 4 + 2], a3 = As[k][tr * 4 + 3];
            float b0 = Bs[k][tc * 4 + 0], b1 = Bs[k][tc * 4 + 1];
            float b2 = Bs[k][tc * 4 + 2], b3 = Bs[k][tc * 4 + 3];
            acc[0][0] += a0 * b0; acc[0][1] += a0 * b1; acc[0][2] += a0 * b2; acc[0][3] += a0 * b3;
            acc[1][0] += a1 * b0; acc[1][1] += a1 * b1; acc[1][2] += a1 * b2; acc[1][3] += a1 * b3;
            acc[2][0] += a2 * b0; acc[2][1] += a2 * b1; acc[2][2] += a2 * b2; acc[2][3] += a2 * b3;
            acc[3][0] += a3 * b0; acc[3][1] += a3 * b1; acc[3][2] += a3 * b2; acc[3][3] += a3 * b3;
        }
        __syncthreads();
    }

    #pragma unroll
    for (int i = 0; i < 4; ++i) {
        const size_t row = (size_t)(bm + tr * 4 + i);
        #pragma unroll
        for (int j = 0; j < 4; ++j) {
            const int col = bn + tc * 4 + j;
            XW[row * DH + col] = acc[i][j] + b[col];
        }
    }
}

// ---------------- Kernel B (R4) ---------------------------------------------
// Thread layout (512 thr): cp = tid&63 -> column pair, s = tid>>6 -> k-slice
//   cols  c0 = part*128 + cp*2, c0+1 ; k in [s*64, s*64+64)
// Weights: float2 wv[64] = Wh[s*64+k][c0..c0+1]  (128 VGPRs, pinned)
__global__ __launch_bounds__(512, 2) void rnn_rec4c(
    const float* __restrict__ Wh,            // (512, 512)
    const float* __restrict__ h0,            // (64, 512)
    float* __restrict__ out,                 // (64, 512, 512); xw on entry
    unsigned long long* __restrict__ hbuf)   // (2, 64, 512) tagged h (d_ws)
{
    __shared__ float hsh[DH];
    __shared__ float partb[8][DH / 4];   // 8 k-slices x 128 cols

    const int bid  = blockIdx.x;
    // all 4 parts of a sequence share bid&7 -> same XCD under round-robin
    // (latency heuristic only; correctness is placement-independent)
    const int xcd  = bid & 7;
    const int idx  = bid >> 3;           // 0..31
    const int seq  = xcd * 8 + (idx & 7);
    const int part = idx >> 3;           // 0..3
    const int tid  = threadIdx.x;
    const int cp   = tid & 63;
    const int s    = tid >> 6;           // 0..7 (wave index)
    const int colbase = part * 128;
    const int c0   = colbase + cp * 2;

    // ---- one-time: weight slice into registers, then pin ----
    float2 wv[64];
    #pragma unroll
    for (int k = 0; k < 64; ++k)
        wv[k] = *(const float2*)&Wh[(size_t)(s * 64 + k) * DH + c0];
    #pragma unroll
    for (int k = 0; k < 64; ++k)
        asm volatile("" : "+v"(wv[k].x), "+v"(wv[k].y));

    if (tid < DH) hsh[tid] = h0[(size_t)seq * DH + tid];
    __syncthreads();

    float* __restrict__ outn = out + (size_t)seq * TSTEPS * DH;
    const int mycol = colbase + tid;     // valid for tid < 128
    float xw_cur = (tid < 128) ? outn[mycol] : 0.0f;

    // remote slot for poll threads (tid 128..511 -> 384 remote cols)
    const int r = tid - 128;
    const int rcol = (r < colbase) ? r : (r + 128);

    for (int t = 0; t < TSTEPS; ++t) {
        // prefetch next xw early (consumed after the compute phase)
        float xw_next = 0.0f;
        if (tid < 128 && t < TSTEPS - 1)
            xw_next = outn[(size_t)(t + 1) * DH + mycol];

        // ---- partial dot: 64 k x 2 cols; h via uniform (broadcast) LDS reads
        float a0 = 0.0f, a1 = 0.0f;
        #pragma unroll
        for (int q = 0; q < 16; ++q) {
            const float4 h4 = *(const float4*)&hsh[s * 64 + q * 4];
            a0 += h4.x * wv[4 * q + 0].x; a1 += h4.x * wv[4 * q + 0].y;
            a0 += h4.y * wv[4 * q + 1].x; a1 += h4.y * wv[4 * q + 1].y;
            a0 += h4.z * wv[4 * q + 2].x; a1 += h4.z * wv[4 * q + 2].y;
            a0 += h4.w * wv[4 * q + 3].x; a1 += h4.w * wv[4 * q + 3].y;
        }
        partb[s][cp * 2 + 0] = a0;
        partb[s][cp * 2 + 1] = a1;
        __syncthreads();    // partb ready; hsh free to overwrite

        unsigned long long* hb = &hbuf[((size_t)(t & 1) * NSEQ + seq) * DH];

        if (tid < 128) {
            // ---- waves 0-1: reduce + tanh + publish own 128 cols ----
            float ssum = partb[0][tid] + partb[1][tid] + partb[2][tid] + partb[3][tid]
                       + partb[4][tid] + partb[5][tid] + partb[6][tid] + partb[7][tid];
            const float hval = tanhf(xw_cur + ssum);
            hsh[mycol] = hval;
            if (t < TSTEPS - 1) {
                const unsigned long long v =
                    ((unsigned long long)(unsigned)(t + 1) << 32) |
                    (unsigned long long)__float_as_uint(hval);
                __hip_atomic_store(&hb[mycol], v,
                                   __ATOMIC_RELAXED, __HIP_MEMORY_SCOPE_AGENT);
            }
            outn[(size_t)t * DH + mycol] = hval;   // off critical path
            xw_cur = xw_next;
        } else if (t < TSTEPS - 1) {
            // ---- waves 2-7: poll one remote slot each (tag == data word) ----
            unsigned long long v;
            do {
                v = __hip_atomic_load(&hb[rcol], __ATOMIC_RELAXED,
                                      __HIP_MEMORY_SCOPE_AGENT);
            } while ((unsigned)(v >> 32) < (unsigned)(t + 1));
            hsh[rcol] = __uint_as_float((unsigned)v);
        }
        __syncthreads();    // hsh complete for step t+1
    }
}

// ---------------- Fallback (R1 kernel) if ws_size is too small --------------
__global__ __launch_bounds__(1024) void rnn_rec(
    const float* __restrict__ Wh,
    const float* __restrict__ h0,
    float* __restrict__ out)
{
    __shared__ float hsh[DH];
    __shared__ float part[8][DH];

    const int n     = blockIdx.x;
    const int tid   = threadIdx.x;
    const int jgrp  = tid & 127;
    const int ks    = tid >> 7;
    const int kbase = ks * 64;

    if (tid < DH) hsh[tid] = h0[(size_t)n * DH + tid];
    __syncthreads();

    const float4* __restrict__ Wh4 = (const float4*)Wh;
    float* __restrict__ outn = out + (size_t)n * TSTEPS * DH;

    float xw_cur = (tid < DH) ? outn[tid] : 0.0f;

    for (int t = 0; t < TSTEPS; ++t) {
        float xw_next = 0.0f;
        if (tid < DH && t < TSTEPS - 1) xw_next = outn[(size_t)(t + 1) * DH + tid];

        float4 acc = {0.0f, 0.0f, 0.0f, 0.0f};
        #pragma unroll 8
        for (int k = 0; k < 64; ++k) {
            const float hk = hsh[kbase + k];
            const float4 w = Wh4[(size_t)(kbase + k) * 128 + jgrp];
            acc.x += hk * w.x; acc.y += hk * w.y;
            acc.z += hk * w.z; acc.w += hk * w.w;
        }
        *(float4*)&part[ks][jgrp * 4] = acc;
        __syncthreads();

        if (tid < DH) {
            const int j = tid;
            float sum = part[0][j] + part[1][j] + part[2][j] + part[3][j]
                      + part[4][j] + part[5][j] + part[6][j] + part[7][j];
            const float hv = tanhf(xw_cur + sum);
            hsh[j] = hv;
            outn[(size_t)t * DH + j] = hv;
            xw_cur = xw_next;
        }
        __syncthreads();
    }
}

extern "C" void kernel_launch(void* const* d_in, const int* in_sizes, int n_in,
                              void* d_out, int out_size, void* d_ws, size_t ws_size,
                              hipStream_t stream) {
    const float* x  = (const float*)d_in[0];  // (64, 512, 512)
    const float* h0 = (const float*)d_in[1];  // (64, 512)
    const float* Wx = (const float*)d_in[2];  // (512, 512)
    const float* Wh = (const float*)d_in[3];  // (512, 512)
    const float* b  = (const float*)d_in[4];  // (512,)
    float* out = (float*)d_out;               // (64, 512, 512)

    // Kernel A: xw = x @ Wx + b, written into d_out.
    xw_gemm<<<dim3(MTOT / 64, DH / 64), 256, 0, stream>>>(x, Wx, b, out);

    // Workspace: hbuf = (2, 64, 512) u64 tagged slots = 512 KB, zeroed per
    // launch (tag 0 < 1 => step-0 polls can't read stale data; deterministic
    // across graph replays).
    const size_t hbuf_bytes = (size_t)2 * NSEQ * DH * sizeof(unsigned long long);
    if (ws_size >= hbuf_bytes) {
        unsigned long long* hbuf = (unsigned long long*)d_ws;
        hipMemsetAsync(hbuf, 0, hbuf_bytes, stream);
        rnn_rec4c<<<256, 512, 0, stream>>>(Wh, h0, out, hbuf);
    } else {
        rnn_rec<<<NSEQ, 1024, 0, stream>>>(Wh, h0, out);
    }
}

// Round 5
// 890.845 us; speedup vs baseline: 6.5726x; 1.0415x over previous
//
#include <hip/hip_runtime.h>
#include <hip/hip_bf16.h>
#include <cmath>

// Problem: N=64, T=512, D=512, H=512
//   xw = x @ Wx + b                 (parallel GEMM, kernel A -> d_out)
//   h_t = tanh(xw_t + h_{t-1} @ Wh) (sequential, kernel B)
//
// R5: 4 wgs/seq (128-col j-slices), 256 wgs x 512 thr. Restructured sync:
//  - wave s owns k-slice [s*64,+64). Reducer waves (2*part, 2*part+1) produce
//    exactly the h-slice they consume next step -> stays in-wg.
//  - remote waves self-poll their tagged slots (tag==t+1 in the same 8B word)
//    and ds_write into a wave-private LDS slice. No forwarding hop.
//  - partb double-buffered by t&1 -> ONE __syncthreads per step (R4 had 2 plus
//    a poller->compute LDS forwarding hop on the critical path).
// Critical path/step: publish -> L3 transit -> remote FMA -> barrier ->
// reduce+tanh -> publish. Predicted ~0.6-0.8 us/step.

#define DH     512
#define NSEQ   64
#define TSTEPS 512
#define MTOT   32768   // N*T

typedef float v2f __attribute__((ext_vector_type(2)));

// ---------------- Kernel A: xw = x @ Wx + b  (fp32 LDS-tiled GEMM) ----------
__global__ __launch_bounds__(256) void xw_gemm(
    const float* __restrict__ X,    // (32768, 512)
    const float* __restrict__ Wx,   // (512, 512)
    const float* __restrict__ b,    // (512,)
    float* __restrict__ XW)         // (32768, 512) == d_out
{
    __shared__ float As[16][64];
    __shared__ float Bs[16][64];

    const int bm = blockIdx.x * 64;
    const int bn = blockIdx.y * 64;
    const int tid = threadIdx.x;
    const int tr = tid >> 4;
    const int tc = tid & 15;

    float acc[4][4] = {};

    for (int k0 = 0; k0 < DH; k0 += 16) {
        {
            int m  = tid >> 2;
            int kk = (tid & 3) * 4;
            const float4 v = *(const float4*)&X[(size_t)(bm + m) * DH + k0 + kk];
            As[kk + 0][m] = v.x; As[kk + 1][m] = v.y;
            As[kk + 2][m] = v.z; As[kk + 3][m] = v.w;
        }
        {
            int k  = tid >> 4;
            int j4 = (tid & 15) * 4;
            *(float4*)&Bs[k][j4] = *(const float4*)&Wx[(size_t)(k0 + k) * DH + bn + j4];
        }
        __syncthreads();

        #pragma unroll
        for (int k = 0; k < 16; ++k) {
            float a0 = As[k][tr * 4 + 0], a1 = As[k][tr * 4 + 1];
            float a2 = As[k][tr * 4 + 2], a3 = As[k][tr * 4 + 3];
            float b0 = Bs[k][tc * 4 + 0], b1 = Bs[k][tc * 4 + 1];
            float b2 = Bs[k][tc * 4 + 2], b3 = Bs[k][tc * 4 + 3];
            acc[0][0] += a0 * b0; acc[0][1] += a0 * b1; acc[0][2] += a0 * b2; acc[0][3] += a0 * b3;
            acc[1][0] += a1 * b0; acc[1][1] += a1 * b1; acc[1][2] += a1 * b2; acc[1][3] += a1 * b3;
            acc[2][0] += a2 * b0; acc[2][1] += a2 * b1; acc[2][2] += a2 * b2; acc[2][3] += a2 * b3;
            acc[3][0] += a3 * b0; acc[3][1] += a3 * b1; acc[3][2] += a3 * b2; acc[3][3] += a3 * b3;
        }
        __syncthreads();
    }

    #pragma unroll
    for (int i = 0; i < 4; ++i) {
        const size_t row = (size_t)(bm + tr * 4 + i);
        #pragma unroll
        for (int j = 0; j < 4; ++j) {
            const int col = bn + tc * 4 + j;
            XW[row * DH + col] = acc[i][j] + b[col];
        }
    }
}

// ---------------- Kernel B (R5) ---------------------------------------------
// 512 thr = 8 waves. lane = tid&63, s = tid>>6.
// Wave s: FMA partials for all 128 own cols over k in [s*64, s*64+64).
//   per lane: cols c0 = colbase+lane*2, c0+1; weights v2f wv[64] (128 VGPRs).
// Reducer waves (s == 2*part + r, r in {0,1}): col q = r*64+lane of own part;
//   their FMA h-slice [s*64,+64) == their own reduce output -> register/LDS
//   local, zero remote wait on own data.
// Remote waves: lane polls tagged slot s*64+lane, ds_write wave-private slice.
__global__ __launch_bounds__(512, 2) void rnn_rec5(
    const float* __restrict__ Wh,            // (512, 512)
    const float* __restrict__ h0,            // (64, 512)
    float* __restrict__ out,                 // (64, 512, 512); xw on entry
    unsigned long long* __restrict__ hbuf)   // (2, 64, 512) tagged h (d_ws)
{
    __shared__ float hslice[8][64];          // wave-private h slices
    __shared__ float partb[2][8][128];       // double-buffered partials

    const int bid  = blockIdx.x;
    // all 4 parts of a seq share bid&7 -> same XCD under round-robin (heuristic)
    const int xcd  = bid & 7;
    const int idx  = bid >> 3;
    const int seq  = xcd * 8 + (idx & 7);
    const int part = idx >> 3;               // 0..3
    const int tid  = threadIdx.x;
    const int lane = tid & 63;
    const int s    = tid >> 6;                // wave 0..7
    const int colbase = part * 128;
    const int c0   = colbase + lane * 2;      // FMA output col pair

    // ---- one-time: weight slice into registers, pinned ----
    v2f wv[64];
    #pragma unroll
    for (int k = 0; k < 64; ++k)
        wv[k] = *(const v2f*)&Wh[(size_t)(s * 64 + k) * DH + c0];
    #pragma unroll
    for (int k = 0; k < 64; ++k)
        asm volatile("" : "+v"(wv[k]));

    // roles
    const int rwave = s - 2 * part;                      // 0/1 => reducer
    const bool is_reducer = (rwave == 0) | (rwave == 1);
    const int q     = rwave * 64 + lane;                 // col idx in part
    const int mycol = colbase + q;                       // global col (reducer)
    const int slot  = s * 64 + lane;                     // h index this lane feeds

    // init wave-private h slice from h0 (compiler inserts lgkmcnt before reads)
    hslice[s][lane] = h0[(size_t)seq * DH + slot];

    float* __restrict__ outn = out + (size_t)seq * TSTEPS * DH;
    float xw_cur = is_reducer ? outn[mycol] : 0.0f;      // xw[0][mycol]

    for (int t = 0; t < TSTEPS; ++t) {
        const int buf = t & 1;

        // ---- phase A: partial FMA over own k-slice (all 8 waves) ----
        v2f acc = {0.0f, 0.0f};
        #pragma unroll
        for (int qq = 0; qq < 16; ++qq) {
            const float4 h4 = *(const float4*)&hslice[s][qq * 4];
            v2f hb;
            hb.x = h4.x; hb.y = h4.x; acc = __builtin_elementwise_fma(hb, wv[4*qq+0], acc);
            hb.x = h4.y; hb.y = h4.y; acc = __builtin_elementwise_fma(hb, wv[4*qq+1], acc);
            hb.x = h4.z; hb.y = h4.z; acc = __builtin_elementwise_fma(hb, wv[4*qq+2], acc);
            hb.x = h4.w; hb.y = h4.w; acc = __builtin_elementwise_fma(hb, wv[4*qq+3], acc);
        }
        *(v2f*)&partb[buf][s][lane * 2] = acc;
        __syncthreads();   // the ONLY barrier per step

        // ---- phase B ----
        unsigned long long* hb64 = &hbuf[((size_t)buf * NSEQ + seq) * DH];
        if (is_reducer) {
            float ssum = partb[buf][0][q] + partb[buf][1][q]
                       + partb[buf][2][q] + partb[buf][3][q]
                       + partb[buf][4][q] + partb[buf][5][q]
                       + partb[buf][6][q] + partb[buf][7][q];
            const float hval = tanhf(xw_cur + ssum);
            if (t < TSTEPS - 1) {
                const unsigned long long v =
                    ((unsigned long long)(unsigned)(t + 1) << 32) |
                    (unsigned long long)__float_as_uint(hval);
                __hip_atomic_store(&hb64[mycol], v,
                                   __ATOMIC_RELAXED, __HIP_MEMORY_SCOPE_AGENT);
            }
            // own next-step data: slot == mycol for reducer waves
            hslice[s][lane] = hval;
            outn[(size_t)t * DH + mycol] = hval;          // off critical path
            if (t < TSTEPS - 1)
                xw_cur = outn[(size_t)(t + 1) * DH + mycol];
        } else if (t < TSTEPS - 1) {
            // remote wave: poll own tagged slot (producer = partner wg reducer)
            unsigned long long v;
            do {
                v = __hip_atomic_load(&hb64[slot], __ATOMIC_RELAXED,
                                      __HIP_MEMORY_SCOPE_AGENT);
            } while ((unsigned)(v >> 32) < (unsigned)(t + 1));
            hslice[s][lane] = __uint_as_float((unsigned)v);
        }
        // no second barrier: hslice is wave-private, partb double-buffered
    }
}

// ---------------- Fallback (R1 kernel) if ws_size is too small --------------
__global__ __launch_bounds__(1024) void rnn_rec(
    const float* __restrict__ Wh,
    const float* __restrict__ h0,
    float* __restrict__ out)
{
    __shared__ float hsh[DH];
    __shared__ float part[8][DH];

    const int n     = blockIdx.x;
    const int tid   = threadIdx.x;
    const int jgrp  = tid & 127;
    const int ks    = tid >> 7;
    const int kbase = ks * 64;

    if (tid < DH) hsh[tid] = h0[(size_t)n * DH + tid];
    __syncthreads();

    const float4* __restrict__ Wh4 = (const float4*)Wh;
    float* __restrict__ outn = out + (size_t)n * TSTEPS * DH;

    float xw_cur = (tid < DH) ? outn[tid] : 0.0f;

    for (int t = 0; t < TSTEPS; ++t) {
        float xw_next = 0.0f;
        if (tid < DH && t < TSTEPS - 1) xw_next = outn[(size_t)(t + 1) * DH + tid];

        float4 acc = {0.0f, 0.0f, 0.0f, 0.0f};
        #pragma unroll 8
        for (int k = 0; k < 64; ++k) {
            const float hk = hsh[kbase + k];
            const float4 w = Wh4[(size_t)(kbase + k) * 128 + jgrp];
            acc.x += hk * w.x; acc.y += hk * w.y;
            acc.z += hk * w.z; acc.w += hk * w.w;
        }
        *(float4*)&part[ks][jgrp * 4] = acc;
        __syncthreads();

        if (tid < DH) {
            const int j = tid;
            float sum = part[0][j] + part[1][j] + part[2][j] + part[3][j]
                      + part[4][j] + part[5][j] + part[6][j] + part[7][j];
            const float hv = tanhf(xw_cur + sum);
            hsh[j] = hv;
            outn[(size_t)t * DH + j] = hv;
            xw_cur = xw_next;
        }
        __syncthreads();
    }
}

extern "C" void kernel_launch(void* const* d_in, const int* in_sizes, int n_in,
                              void* d_out, int out_size, void* d_ws, size_t ws_size,
                              hipStream_t stream) {
    const float* x  = (const float*)d_in[0];  // (64, 512, 512)
    const float* h0 = (const float*)d_in[1];  // (64, 512)
    const float* Wx = (const float*)d_in[2];  // (512, 512)
    const float* Wh = (const float*)d_in[3];  // (512, 512)
    const float* b  = (const float*)d_in[4];  // (512,)
    float* out = (float*)d_out;               // (64, 512, 512)

    // Kernel A: xw = x @ Wx + b, written into d_out.
    xw_gemm<<<dim3(MTOT / 64, DH / 64), 256, 0, stream>>>(x, Wx, b, out);

    // Workspace: hbuf = (2, 64, 512) u64 tagged slots = 512 KB, zeroed per
    // launch (tag 0 < 1 => step-0 polls can't see stale; graph-replay safe).
    const size_t hbuf_bytes = (size_t)2 * NSEQ * DH * sizeof(unsigned long long);
    if (ws_size >= hbuf_bytes) {
        unsigned long long* hbuf = (unsigned long long*)d_ws;
        hipMemsetAsync(hbuf, 0, hbuf_bytes, stream);
        rnn_rec5<<<256, 512, 0, stream>>>(Wh, h0, out, hbuf);
    } else {
        rnn_rec<<<NSEQ, 1024, 0, stream>>>(Wh, h0, out);
    }
}